// Round 10
// baseline (1791.234 us; speedup 1.0000x reference)
//
#include <hip/hip_runtime.h>
#include <hip/hip_bf16.h>

#define BB 64
#define CC 32
#define HW2 256   // 16*16
#define VV 4096
#define NELEM (BB*CC*HW2)   // 524288
#define PADW 18
#define PADA 324  // 18*18
#define NBLK 256
#define NTHR 512

// ---------------- workspace layout (float offsets) ----------------
#define OFF_F     0
#define OFF_FHAT  (OFF_F     + NELEM)        // 524288
#define OFF_EMBT  (OFF_FHAT  + NELEM)        // 1048576 (tile-major codebook)
#define OFF_ESQ   (OFF_EMBT  + VV*CC)        // 1179648
#define OFF_PW    (OFF_ESQ   + VV)           // 1183744
#define OFF_PB    (OFF_PW    + 4*CC*CC*9)    // 1220608
#define OFF_REST  (OFF_PB    + 4*CC)         // 1220736 (row-major, 16384*32)
#define OFF_BESTA (OFF_REST  + 16384*CC)     // 1745024 (16384 u64)
#define OFF_BESTB (OFF_BESTA + 2*16384)      // 1777792
#define OFF_LOSS  (OFF_BESTB + 2*16384)      // 1810560
#define OFF_FLAG  (OFF_LOSS  + 1)
#define OFF_BAR   (OFF_FLAG  + 1)            // 32 ints

// embT layout: embT[v>>6][c][v&63]  (tile stride 2048 floats, row stride 64)
__device__ __forceinline__ int embt_idx(int v, int c) {
    return (v >> 6) * 2048 + c * 64 + (v & 63);
}

// ---------------- dtype probe: is input 0 f32 (1) or bf16 (0)? ----------------
__global__ void k_probe(const void* __restrict__ fin, int* __restrict__ flag) {
    __shared__ int cnt[256];
    int t = threadIdx.x;
    const __hip_bfloat16* p = (const __hip_bfloat16*)fin;
    int local = 0;
    for (int i = t; i < 8192; i += 256) {
        float v = __bfloat162float(p[i]);
        if (!(fabsf(v) < 1e3f)) local++;
    }
    cnt[t] = local;
    __syncthreads();
    for (int s = 128; s > 0; s >>= 1) {
        if (t < s) cnt[t] += cnt[t + s];
        __syncthreads();
    }
    if (t == 0) *flag = (cnt[0] >= 64) ? 1 : 0;
}

// ---------------- prep: decode -> f32 ws; zero fhat/loss/barriers -------------
__global__ void k_prep(const void* __restrict__ fin,
                       const void* __restrict__ ein,
                       const void* __restrict__ win,
                       const void* __restrict__ bin_,
                       const int* __restrict__ flag,
                       float* __restrict__ f, float* __restrict__ fhat,
                       float* __restrict__ embT, float* __restrict__ pw,
                       float* __restrict__ pb, float* __restrict__ loss,
                       int* __restrict__ bar) {
    bool isf32 = (*flag != 0);
    int i = blockIdx.x * 256 + threadIdx.x;
    if (i < NELEM) {
        f[i] = isf32 ? ((const float*)fin)[i]
                     : __bfloat162float(((const __hip_bfloat16*)fin)[i]);
        fhat[i] = 0.f;
    }
    if (i < VV*CC) {
        float ev = isf32 ? ((const float*)ein)[i]
                         : __bfloat162float(((const __hip_bfloat16*)ein)[i]);
        int v = i >> 5, c = i & 31;
        embT[embt_idx(v, c)] = ev;
    }
    if (i < 4*CC*CC*9)
        pw[i] = isf32 ? ((const float*)win)[i]
                      : __bfloat162float(((const __hip_bfloat16*)win)[i]);
    if (i < 4*CC)
        pb[i] = isf32 ? ((const float*)bin_)[i]
                      : __bfloat162float(((const __hip_bfloat16*)bin_)[i]);
    if (i < 32) bar[i] = 0;
    if (i == 0) *loss = 0.f;
}

// ---------------- grid barrier (monotonic counters, device-scope fences) ------
__device__ __forceinline__ void gsync(int* bar, int idx) {
    __threadfence();                 // release our global writes
    __syncthreads();
    if (threadIdx.x == 0) {
        atomicAdd(&bar[idx], 1);
        while (atomicAdd(&bar[idx], 0) < NBLK) __builtin_amdgcn_s_sleep(2);
    }
    __syncthreads();
    __threadfence();                 // acquire others' writes
}

// ---------------- persistent kernel: esq+pool0, 8x(argmin, fuse), out ---------
__global__ __launch_bounds__(NTHR, 2)
void k_persist(float* __restrict__ rest, const float* __restrict__ embT,
               float* __restrict__ esq,
               unsigned long long* __restrict__ bestA,
               unsigned long long* __restrict__ bestB,
               const float* __restrict__ pw, const float* __restrict__ pb,
               const float* __restrict__ f, float* __restrict__ fhat,
               float* __restrict__ loss, const int* __restrict__ flag,
               void* __restrict__ out, int* __restrict__ bar) {
    __shared__ __align__(16) float smem[15784];   // 63136 B union
    // argmin views
    float (*xT)[260] = (float(*)[260])smem;       // 32*260 = 8320 floats
    float* eT  = smem + 8320;                     // 2048 floats (16B-aligned)
    float* xxs = smem + 10368;                    // 512 floats [2][256]
    // fuse views
    float* h_pad = smem;                          // 32*324 = 10368
    float* extra = smem + 10368;                  // 32*169 = 5408
    float* red   = smem + 15776;                  // 8

    const int PNa[8] = {1, 2, 4, 6, 8, 10, 13, 16};
    const int SPa[8] = {64, 64, 64, 32, 16, 8, 8, 4};
    const int KKa[8] = {0, 0, 1, 1, 2, 2, 3, 3};

    int blk = blockIdx.x, t = threadIdx.x;

    // ---- prologue: esq + pool0 + bestA init ----
    {
        int g = blk * NTHR + t;
        if (g < VV) {
            const float* p = embT + (g >> 6) * 2048 + (g & 63);
            float s = 0.f;
            #pragma unroll
            for (int c = 0; c < CC; ++c) { float e = p[c * 64]; s = fmaf(e, e, s); }
            esq[g] = s;
        }
        int p0 = g - 8192;
        if (p0 >= 0 && p0 < BB * CC) {
            int n = p0 >> 5, c = p0 & 31;
            const float* fb = f + (n * CC + c) * HW2;
            float s = 0.f;
            for (int h = 0; h < 16; ++h)
                for (int w = 0; w < 16; ++w)
                    s += fb[h * 16 + w];          // fhat == 0 at scale 0
            rest[n * CC + c] = s * (1.f / 256.f);
            if (c == 0) bestA[n] = 0xFFFFFFFFFFFFFFFFull;
        }
    }
    gsync(bar, 0);

    int bidx = 1;
    for (int si = 0; si < 8; ++si) {
        int pn = PNa[si], Sp = SPa[si], k = KKa[si];
        int Ntot = BB * pn * pn;
        int gxq = (Ntot + 255) >> 8;
        int cpw = VV / Sp;
        int units = gxq * Sp;
        unsigned long long* bcur = (si & 1) ? bestB : bestA;
        unsigned long long* bnxt = (si & 1) ? bestA : bestB;
        int pn_next = (si < 7) ? PNa[si + 1] : 0;

        // ================= argmin phase =================
        int tx = t & 15, ty = t >> 4;     // code lane, query group
        for (int u = blk; u < units; u += NBLK) {
            int qblk = (u % gxq) * 256;
            int v0 = (u / gxq) * cpw;
            int t0 = v0 >> 6;

            __syncthreads();   // prior unit's LDS reads complete
            // stage xT (transpose 256 queries) + partial xx
            {
                int q = t >> 1, h = t & 1;
                int qq = qblk + q; if (qq > Ntot - 1) qq = Ntot - 1;
                const float* xr = rest + qq * CC + h * 16;
                float part = 0.f;
                #pragma unroll
                for (int c = 0; c < 16; ++c) {
                    float xv = xr[c];
                    xT[h * 16 + c][q] = xv;
                    part = fmaf(xv, xv, part);
                }
                xxs[h * 256 + q] = part;
            }
            __syncthreads();

            float xx[8];
            #pragma unroll
            for (int i = 0; i < 8; ++i) {
                int q = ty * 8 + i;
                xx[i] = xxs[q] + xxs[256 + q];
            }
            float bd[8]; int bi[8];
            #pragma unroll
            for (int i = 0; i < 8; ++i) { bd[i] = 3.4e38f; bi[i] = v0; }

            int ntiles = cpw >> 6;
            for (int tt = 0; tt < ntiles; ++tt) {
                int vbase = v0 + tt * 64;
                float4 s0 = ((const float4*)(embT + (size_t)(t0 + tt) * 2048))[t];
                __syncthreads();
                ((float4*)eT)[t] = s0;
                __syncthreads();

                float acc[8][4];
                #pragma unroll
                for (int i = 0; i < 8; ++i)
                    #pragma unroll
                    for (int j = 0; j < 4; ++j) acc[i][j] = 0.f;

                #pragma unroll 8
                for (int kk = 0; kk < CC; ++kk) {
                    float4 a0 = *(const float4*)&xT[kk][ty * 8];
                    float4 a1 = *(const float4*)&xT[kk][ty * 8 + 4];
                    float4 b4 = *(const float4*)&eT[kk * 64 + tx * 4];
                    float a[8] = {a0.x, a0.y, a0.z, a0.w, a1.x, a1.y, a1.z, a1.w};
                    float b[4] = {b4.x, b4.y, b4.z, b4.w};
                    #pragma unroll
                    for (int i = 0; i < 8; ++i)
                        #pragma unroll
                        for (int j = 0; j < 4; ++j)
                            acc[i][j] = fmaf(a[i], b[j], acc[i][j]);
                }

                float4 es4 = *(const float4*)(esq + vbase + tx * 4);
                float es[4] = {es4.x, es4.y, es4.z, es4.w};
                #pragma unroll
                for (int i = 0; i < 8; ++i) {
                    float base = xx[i];
                    #pragma unroll
                    for (int j = 0; j < 4; ++j) {
                        float dist = fmaf(-2.f, acc[i][j], base + es[j]);
                        if (dist < bd[i]) { bd[i] = dist; bi[i] = vbase + tx * 4 + j; }
                    }
                }
            }

            #pragma unroll
            for (int i = 0; i < 8; ++i) {
                unsigned uu = __float_as_uint(bd[i]);
                unsigned long long mono = (uu & 0x80000000u)
                    ? (unsigned long long)(~uu)
                    : (unsigned long long)(uu | 0x80000000u);
                unsigned long long pk = (mono << 32) | (unsigned long long)(unsigned)bi[i];
                #pragma unroll
                for (int m = 1; m <= 8; m <<= 1) {
                    unsigned long long o = __shfl_xor(pk, m, 64);
                    if (o < pk) pk = o;
                }
                int q = qblk + ty * 8 + i;
                if (tx == 0 && q < Ntot)
                    atomicMin(bcur + q, pk);
            }
        }
        gsync(bar, bidx++);

        // ================= fuse phase (unit = blk) =================
        {
            int b = blk >> 2, coq = blk & 3;
            int nn = pn * pn;
            int pix = t & 255, half = t >> 8;
            int y = pix >> 4, x = pix & 15;
            int c0 = half * 16;

            for (int i = t; i < CC * PADA; i += NTHR) h_pad[i] = 0.f;

            if (pn == 16) {
                __syncthreads();
                int id = (int)(unsigned)(bcur[b * HW2 + pix] & 0xFFFFFFFFull);
                const float* er = embT + (id >> 6) * 2048 + (id & 63);
                int ctr = (y + 1) * PADW + (x + 1);
                #pragma unroll
                for (int c = 0; c < 16; ++c)
                    h_pad[(c0 + c) * PADA + ctr] = er[(c0 + c) * 64];
            } else {
                float (*hs)[169] = (float(*)[169])extra;
                for (int cell = t; cell < nn; cell += NTHR) {
                    int id = (int)(unsigned)(bcur[b * nn + cell] & 0xFFFFFFFFull);
                    const float* er = embT + (id >> 6) * 2048 + (id & 63);
                    #pragma unroll
                    for (int c = 0; c < CC; ++c) hs[c][cell] = er[c * 64];
                }
                __syncthreads();
                float scale = (float)pn / 16.f;
                float sy = (y + 0.5f) * scale - 0.5f;
                sy = fminf(fmaxf(sy, 0.f), (float)(pn - 1));
                int y0 = (int)sy; int y1 = min(y0 + 1, pn - 1); float wy = sy - (float)y0;
                float sx = (x + 0.5f) * scale - 0.5f;
                sx = fminf(fmaxf(sx, 0.f), (float)(pn - 1));
                int x0 = (int)sx; int x1 = min(x0 + 1, pn - 1); float wx = sx - (float)x0;
                float wy0 = 1.f - wy, wx0 = 1.f - wx;
                int ctr = (y + 1) * PADW + (x + 1);
                #pragma unroll
                for (int c = 0; c < 16; ++c) {
                    int cc = c0 + c;
                    float v00 = hs[cc][y0 * pn + x0], v01 = hs[cc][y0 * pn + x1];
                    float v10 = hs[cc][y1 * pn + x0], v11 = hs[cc][y1 * pn + x1];
                    float a0 = wy0 * v00 + wy * v10;   // contract H first (jax order)
                    float a1 = wy0 * v01 + wy * v11;
                    h_pad[cc * PADA + ctr] = wx0 * a0 + wx * a1;
                }
            }
            __syncthreads();

            float acc[4];
            #pragma unroll
            for (int o = 0; o < 4; ++o) acc[o] = 0.f;
            const float* hbase = h_pad + y * PADW + x;
            const float* wpk = pw + (k * CC + coq * 8 + half * 4) * (CC * 9);
            #pragma unroll
            for (int ci_ = 0; ci_ < CC; ++ci_) {
                float hv[9];
                #pragma unroll
                for (int dy = 0; dy < 3; ++dy)
                    #pragma unroll
                    for (int dx = 0; dx < 3; ++dx)
                        hv[dy * 3 + dx] = hbase[ci_ * PADA + dy * PADW + dx];
                const float* wp = wpk + ci_ * 9;
                #pragma unroll
                for (int o = 0; o < 4; ++o) {
                    const float* w9 = wp + o * (CC * 9);
                    #pragma unroll
                    for (int q = 0; q < 9; ++q) acc[o] = fmaf(hv[q], w9[q], acc[o]);
                }
            }

            float* diff = extra;
            float lsum = 0.f;
            int ctr = (y + 1) * PADW + (x + 1);
            #pragma unroll
            for (int o = 0; o < 4; ++o) {
                int lo = half * 4 + o;
                int co = coq * 8 + lo;
                float hval = h_pad[co * PADA + ctr];
                float outv = hval * 0.5f + (acc[o] + pb[k * CC + co]) * 0.5f;
                int pos = (b * CC + co) * HW2 + pix;
                float fh = fhat[pos] + outv;
                fhat[pos] = fh;
                float dd = f[pos] - fh;
                diff[lo * HW2 + pix] = dd;
                lsum = fmaf(dd, dd, lsum);
            }
            #pragma unroll
            for (int off = 32; off > 0; off >>= 1) lsum += __shfl_down(lsum, off, 64);
            if ((t & 63) == 0) red[t >> 6] = lsum;
            __syncthreads();
            if (t == 0) {
                float s = 0.f;
                #pragma unroll
                for (int w = 0; w < 8; ++w) s += red[w];
                atomicAdd(loss, s);
            }

            if (pn_next > 0) {
                int nn2 = pn_next * pn_next;
                for (int q = t; q < nn2 * 8; q += NTHR) {
                    int cell = q % nn2, o = q / nn2;
                    int i = cell / pn_next, j = cell % pn_next;
                    int s0 = (i * 16) / pn_next, e0 = ((i + 1) * 16 + pn_next - 1) / pn_next;
                    int s1 = (j * 16) / pn_next, e1 = ((j + 1) * 16 + pn_next - 1) / pn_next;
                    float inv = 1.f / (float)((e0 - s0) * (e1 - s1));
                    float s = 0.f;
                    for (int h = s0; h < e0; ++h)
                        for (int w = s1; w < e1; ++w)
                            s += diff[o * HW2 + h * 16 + w];
                    rest[(b * nn2 + cell) * CC + coq * 8 + o] = s * inv;
                }
                if (coq == 0)
                    for (int q = t; q < nn2; q += NTHR)
                        bnxt[b * nn2 + q] = 0xFFFFFFFFFFFFFFFFull;
            }
        }
        gsync(bar, bidx++);
    }

    // ---- epilogue: writeout ----
    bool isf32 = (*flag != 0);
    for (int i = blk * NTHR + t; i <= NELEM; i += NBLK * NTHR) {
        float v;
        if (i < NELEM) v = fhat[i];
        else           v = (*loss) * (1.25f / (float)NELEM / 8.f);
        if (isf32) ((float*)out)[i] = v;
        else       ((__hip_bfloat16*)out)[i] = __float2bfloat16(v);
    }
}

extern "C" void kernel_launch(void* const* d_in, const int* in_sizes, int n_in,
                              void* d_out, int out_size, void* d_ws, size_t ws_size,
                              hipStream_t stream) {
    const void* fin  = d_in[0];
    const void* ein  = d_in[1];
    const void* win  = d_in[2];
    const void* bin_ = d_in[3];
    float* ws = (float*)d_ws;
    float* f    = ws + OFF_F;
    float* fhat = ws + OFF_FHAT;
    float* embT = ws + OFF_EMBT;
    float* esq  = ws + OFF_ESQ;
    float* pw   = ws + OFF_PW;
    float* pb   = ws + OFF_PB;
    float* rest = ws + OFF_REST;
    unsigned long long* bestA = (unsigned long long*)(ws + OFF_BESTA);
    unsigned long long* bestB = (unsigned long long*)(ws + OFF_BESTB);
    float* loss = ws + OFF_LOSS;
    int*   flag = (int*)(ws + OFF_FLAG);
    int*   bar  = (int*)(ws + OFF_BAR);

    k_probe<<<1, 256, 0, stream>>>(fin, flag);
    k_prep<<<(NELEM + 255) / 256, 256, 0, stream>>>(fin, ein, win, bin_, flag,
                                                    f, fhat, embT, pw, pb, loss, bar);
    k_persist<<<NBLK, NTHR, 0, stream>>>(rest, embT, esq, bestA, bestB, pw, pb,
                                         f, fhat, loss, flag, d_out, bar);
}